// Round 1
// baseline (655.522 us; speedup 1.0000x reference)
//
#include <hip/hip_runtime.h>

#define N 512
#define EMB 256
#define MARGIN 3.0f

// ws layout: ws[0] = loss sum (float), ws[1] = triplet count (float)

__global__ void init_ws_kernel(float* ws) {
    if (threadIdx.x == 0) { ws[0] = 0.0f; ws[1] = 0.0f; }
}

__global__ __launch_bounds__(256) void triplet_kernel(
        const float* __restrict__ emb,
        const int*   __restrict__ labels,
        const float* __restrict__ rand_u,
        float*       __restrict__ ws) {
    __shared__ float e_i[EMB];     // anchor embedding
    __shared__ float D_s[N];       // D[i, :]
    __shared__ int   lab_s[N];

    const int i   = blockIdx.x;
    const int tid = threadIdx.x;

    if (tid < EMB) e_i[tid] = emb[i * EMB + tid];
    lab_s[tid]       = labels[tid];
    lab_s[tid + 256] = labels[tid + 256];
    __syncthreads();

    // sq_i = ||e_i||^2 (per-thread from LDS, cheap)
    float sqi = 0.0f;
    const float4* e4 = (const float4*)e_i;
    #pragma unroll 8
    for (int k = 0; k < EMB / 4; ++k) {
        float4 v = e4[k];
        sqi += v.x * v.x + v.y * v.y + v.z * v.z + v.w * v.w;
    }

    // D[i, j] = sq_i + sq_j - 2 * <e_i, e_j>   (matches reference expansion form)
    for (int j = tid; j < N; j += 256) {
        const float4* g4 = (const float4*)(emb + j * EMB);
        float dot = 0.0f, sqj = 0.0f;
        #pragma unroll 8
        for (int k = 0; k < EMB / 4; ++k) {
            float4 a = e4[k], b = g4[k];
            dot += a.x * b.x + a.y * b.y + a.z * b.z + a.w * b.w;
            sqj += b.x * b.x + b.y * b.y + b.z * b.z + b.w * b.w;
        }
        D_s[j] = sqi + sqj - 2.0f * dot;
    }
    __syncthreads();

    const int wave  = tid >> 6;
    const int lane  = tid & 63;
    const int lab_i = lab_s[i];

    float wsum = 0.0f, wcnt = 0.0f;

    // each wave takes every 4th candidate positive j > i
    for (int j = i + 1 + wave; j < N; j += 4) {
        if (lab_s[j] != lab_i) continue;   // wave-uniform branch
        const float  Dij  = D_s[j];
        const float* rrow = rand_u + (size_t)(i * N + j) * N;

        // lane-local best over 8 coalesced strips; strict > keeps first max
        float best_s = -1.0f;
        int   best_n = 0x7fffffff;
        #pragma unroll
        for (int s = 0; s < N / 64; ++s) {
            int   n     = s * 64 + lane;
            float r     = rrow[n];                       // coalesced 256B/wave
            bool  valid = (lab_s[n] != lab_i) && (Dij - D_s[n] + MARGIN > 0.0f);
            float sc    = valid ? r : -1.0f;
            if (sc > best_s) { best_s = sc; best_n = n; }
        }
        // 64-lane reduce; ties -> smaller n (jnp.argmax first-occurrence)
        for (int off = 32; off > 0; off >>= 1) {
            float os = __shfl_down(best_s, off);
            int   on = __shfl_down(best_n, off);
            if (os > best_s || (os == best_s && on < best_n)) {
                best_s = os; best_n = on;
            }
        }
        if (lane == 0 && best_s > -0.5f) {   // any valid negative existed
            float l = Dij - D_s[best_n] + MARGIN;
            wsum += fmaxf(l, 0.0f);
            wcnt += 1.0f;
        }
    }

    if (lane == 0 && wcnt != 0.0f) {
        atomicAdd(&ws[0], wsum);   // device-scope by default (cross-XCD safe)
        atomicAdd(&ws[1], wcnt);
    }
}

__global__ void finalize_kernel(const float* __restrict__ ws,
                                float* __restrict__ out) {
    if (threadIdx.x == 0) {
        float s = ws[0], c = ws[1];
        out[0] = s / fmaxf(c, 1.0f);   // loss = sum / max(n_triplets, 1)
        out[1] = c;                    // n_triplets
    }
}

extern "C" void kernel_launch(void* const* d_in, const int* in_sizes, int n_in,
                              void* d_out, int out_size, void* d_ws, size_t ws_size,
                              hipStream_t stream) {
    const float* emb    = (const float*)d_in[0];   // [512, 256] fp32
    const int*   labels = (const int*)  d_in[1];   // [512] int32
    const float* rand_u = (const float*)d_in[2];   // [512, 512, 512] fp32
    float*       out    = (float*)d_out;           // [2] fp32: loss, n_triplets
    float*       ws     = (float*)d_ws;            // 2 floats of scratch

    init_ws_kernel<<<1, 64, 0, stream>>>(ws);
    triplet_kernel<<<N, 256, 0, stream>>>(emb, labels, rand_u, ws);
    finalize_kernel<<<1, 64, 0, stream>>>(ws, out);
}

// Round 2
// 645.307 us; speedup vs baseline: 1.0158x; 1.0158x over previous
//
#include <hip/hip_runtime.h>

#define N 512
#define EMB 256
#define MARGIN 3.0f

// ws layout (16 bytes used, zeroed via hipMemsetAsync before launch):
//   ws[0] = loss sum (float)
//   ws[1] = triplet count (float)
//   ws[2] = block arrival counter (uint32)

__global__ __launch_bounds__(256) void triplet_kernel(
        const float* __restrict__ emb,
        const float* __restrict__ labels_f,   // cast in launch; real type int
        const float* __restrict__ rand_u,
        float*       __restrict__ ws,
        float*       __restrict__ out) {
    const int* labels = (const int*)labels_f;

    __shared__ float e_i[EMB];     // anchor embedding
    __shared__ float D_s[N];       // D[i, :]
    __shared__ int   lab_s[N];
    __shared__ float red_s[4], red_c[4];

    const int i   = blockIdx.x;
    const int tid = threadIdx.x;

    if (tid < EMB) e_i[tid] = emb[i * EMB + tid];
    lab_s[tid]       = labels[tid];
    lab_s[tid + 256] = labels[tid + 256];
    __syncthreads();

    // sq_i = ||e_i||^2
    float sqi = 0.0f;
    const float4* e4 = (const float4*)e_i;
    #pragma unroll 8
    for (int k = 0; k < EMB / 4; ++k) {
        float4 v = e4[k];
        sqi += v.x * v.x + v.y * v.y + v.z * v.z + v.w * v.w;
    }

    // D[i, j] = sq_i + sq_j - 2 * <e_i, e_j>   (matches reference expansion)
    for (int j = tid; j < N; j += 256) {
        const float4* g4 = (const float4*)(emb + j * EMB);
        float dot = 0.0f, sqj = 0.0f;
        #pragma unroll 8
        for (int k = 0; k < EMB / 4; ++k) {
            float4 a = e4[k], b = g4[k];
            dot += a.x * b.x + a.y * b.y + a.z * b.z + a.w * b.w;
            sqj += b.x * b.x + b.y * b.y + b.z * b.z + b.w * b.w;
        }
        D_s[j] = sqi + sqj - 2.0f * dot;
    }
    __syncthreads();

    const int wave  = tid >> 6;
    const int lane  = tid & 63;
    const int lab_i = lab_s[i];

    float wsum = 0.0f, wcnt = 0.0f;

    // each wave takes every 4th candidate positive j > i
    for (int j = i + 1 + wave; j < N; j += 4) {
        if (lab_s[j] != lab_i) continue;   // wave-uniform branch
        const float  Dij  = D_s[j];
        const float* rrow = rand_u + (size_t)(i * N + j) * N;

        // lane-local best over 8 coalesced strips; strict > keeps first max
        float best_s = -1.0f;
        int   best_n = 0x7fffffff;
        #pragma unroll
        for (int s = 0; s < N / 64; ++s) {
            int   n     = s * 64 + lane;
            float r     = rrow[n];                       // coalesced 256B/wave
            bool  valid = (lab_s[n] != lab_i) && (Dij - D_s[n] + MARGIN > 0.0f);
            float sc    = valid ? r : -1.0f;
            if (sc > best_s) { best_s = sc; best_n = n; }
        }
        // 64-lane reduce; ties -> smaller n (jnp.argmax first-occurrence)
        for (int off = 32; off > 0; off >>= 1) {
            float os = __shfl_down(best_s, off);
            int   on = __shfl_down(best_n, off);
            if (os > best_s || (os == best_s && on < best_n)) {
                best_s = os; best_n = on;
            }
        }
        if (lane == 0 && best_s > -0.5f) {   // some valid negative existed
            float l = Dij - D_s[best_n] + MARGIN;
            wsum += fmaxf(l, 0.0f);
            wcnt += 1.0f;
        }
    }

    // per-block reduction: 4 wave-partials -> 1 atomic pair per block
    if (lane == 0) { red_s[wave] = wsum; red_c[wave] = wcnt; }
    __syncthreads();

    if (tid == 0) {
        float bs = red_s[0] + red_s[1] + red_s[2] + red_s[3];
        float bc = red_c[0] + red_c[1] + red_c[2] + red_c[3];
        if (bc != 0.0f) {
            atomicAdd(&ws[0], bs);   // device-scope by default
            atomicAdd(&ws[1], bc);
        }
        __threadfence();             // order sum-atomics before arrival
        unsigned int old = atomicAdd((unsigned int*)&ws[2], 1u);
        if (old == (unsigned int)(gridDim.x - 1)) {
            // last block: read sums coherently via atomic readback
            float s = atomicAdd(&ws[0], 0.0f);
            float c = atomicAdd(&ws[1], 0.0f);
            out[0] = s / fmaxf(c, 1.0f);   // loss = sum / max(n_triplets,1)
            out[1] = c;                    // n_triplets
        }
    }
}

extern "C" void kernel_launch(void* const* d_in, const int* in_sizes, int n_in,
                              void* d_out, int out_size, void* d_ws, size_t ws_size,
                              hipStream_t stream) {
    const float* emb    = (const float*)d_in[0];   // [512, 256] fp32
    const float* labels = (const float*)d_in[1];   // [512] int32 (cast inside)
    const float* rand_u = (const float*)d_in[2];   // [512, 512, 512] fp32
    float*       out    = (float*)d_out;           // [2] fp32: loss, n_triplets
    float*       ws     = (float*)d_ws;

    hipMemsetAsync(ws, 0, 16, stream);             // zero accum + counter
    triplet_kernel<<<N, 256, 0, stream>>>(emb, labels, rand_u, ws, out);
}